// Round 12
// baseline (645.061 us; speedup 1.0000x reference)
//
#include <hip/hip_runtime.h>
#include <hip/hip_bf16.h>

#define D 128

typedef unsigned int u32;
typedef unsigned short ushort_t;

typedef __attribute__((ext_vector_type(8))) __bf16 bf16x8;
typedef __attribute__((ext_vector_type(4))) float f32x4;

__device__ __forceinline__ float bf2f(ushort_t u){ return __uint_as_float(((u32)u)<<16); }
__device__ __forceinline__ ushort_t f2bf(float f){
  u32 x = __float_as_uint(f);
  return (ushort_t)((x + 0x7fffu + ((x>>16)&1u)) >> 16);
}
// packed dword = two consecutive bf16 elements (lo = even col, hi = odd col)
__device__ __forceinline__ float2 bfp2(u32 w){
  float2 r; r.x = __uint_as_float(w<<16); r.y = __uint_as_float(w & 0xffff0000u); return r;
}
__device__ __forceinline__ u32 packbf(float a, float b){
  return (u32)f2bf(a) | ((u32)f2bf(b)<<16);
}
// hardware packed f32->bf16 (RNE): lo = bf16(a), hi = bf16(b)
__device__ __forceinline__ u32 cvtpk(float a, float b){
  u32 r; asm("v_cvt_pk_bf16_f32 %0, %1, %2" : "=v"(r) : "v"(a), "v"(b)); return r;
}
__device__ __forceinline__ ushort_t cvt1(float a){
  u32 r; asm("v_cvt_pk_bf16_f32 %0, %1, %1" : "=v"(r) : "v"(a)); return (ushort_t)r;
}
// packed bf16 atomic add (gfx940+): one dword = 2 consecutive bf16 elements
__device__ __forceinline__ void atompk(ushort_t* p, u32 v){
  asm volatile("global_atomic_pk_add_bf16 %0, %1, off" :: "v"(p), "v"(v) : "memory");
}
__device__ __forceinline__ float sigm(float x){ return 1.0f/(1.0f+__expf(-x)); }
__device__ __forceinline__ float ftanh(float x){
  float e = __expf(-2.0f*fabsf(x));
  float t = (1.0f-e)/(1.0f+e);
  return copysignf(t,x);
}

// ---------------- fused convert + dtype-detect + init ----------------
struct CvtArgs { const void* src[17]; ushort_t* dst[17]; int n[17]; };

__global__ __launch_bounds__(256) void convert_kernel(CvtArgs a,
  const u32* __restrict__ probe, int* __restrict__ flag,
  u32* __restrict__ aggz, float* __restrict__ sum_exp, int* __restrict__ last_edge, int N)
{
  __shared__ int s_isf;
  int tid = threadIdx.x;
  if (tid < 64){
    int cnt = 0;
    for (int i = tid; i < 512; i += 64){
      u32 w = probe[i];
      u32 e = (w >> 7) & 0xFFu;
      if (e >= 100u && e <= 126u) cnt++;
    }
    #pragma unroll
    for (int off = 32; off > 0; off >>= 1) cnt += __shfl_xor(cnt, off);
    if (tid == 0){
      s_isf = (cnt < 256) ? 1 : 0;
      if (blockIdx.x == 0) *flag = s_isf;
    }
  }
  __syncthreads();
  int isf = s_isf;
  int gid = blockIdx.x*blockDim.x + tid;
  int gs  = gridDim.x*blockDim.x;
  for (int s = 0; s < 17; s++){
    int n = a.n[s];
    ushort_t* dst = a.dst[s];
    int n4 = n >> 2;
    if (isf){
      const float4* src4 = (const float4*)a.src[s];
      uint2* dst4 = (uint2*)dst;
      for (int j = gid; j < n4; j += gs){
        float4 v = src4[j];
        uint2 o; o.x = packbf(v.x, v.y); o.y = packbf(v.z, v.w);
        dst4[j] = o;
      }
      const float* src = (const float*)a.src[s];
      for (int j = (n4<<2) + gid; j < n; j += gs) dst[j] = f2bf(src[j]);
    } else {
      const uint2* src4 = (const uint2*)a.src[s];
      uint2* dst4 = (uint2*)dst;
      for (int j = gid; j < n4; j += gs) dst4[j] = src4[j];
      const ushort_t* src = (const ushort_t*)a.src[s];
      for (int j = (n4<<2) + gid; j < n; j += gs) dst[j] = src[j];
    }
  }
  // init: agg (bf16) zero, sum_exp, last_edge
  int na = N*D/2;
  int na4 = na >> 2;
  uint4 z4 = make_uint4(0,0,0,0);
  for (int j=gid; j<na4; j+=gs) ((uint4*)aggz)[j] = z4;
  for (int j=(na4<<2)+gid; j<na; j+=gs) aggz[j]=0u;
  for (int j=gid; j<N;  j+=gs){ sum_exp[j]=0.f; last_edge[j]=-1; }
}

// ---------------- per-rel and per-query tables (packed triples) ----------------
// RELP[rel][64] = uint3 { (Az0,Az1), (Ar0,Ar1), (Ah0,Ah1) }  per col-pair
// RIDP[q  ][64] = uint3 { (Bz0,Bz1), (Br0,Br1), (Bh0,Bh1) }
// CaT[q][arow*8+t] = Ca[q][t*16+arow]  (C-layout order: 16B/lane in phase 5)
__global__ void table_kernel(const ushort_t* __restrict__ rela,
  const ushort_t* __restrict__ Wz, const ushort_t* __restrict__ Wr, const ushort_t* __restrict__ Wh,
  const ushort_t* __restrict__ Wqr,
  const ushort_t* __restrict__ bz, const ushort_t* __restrict__ br, const ushort_t* __restrict__ bh,
  const ushort_t* __restrict__ bqr,
  const int* __restrict__ q_rel,
  ushort_t* hq_tab, u32* __restrict__ RELP, u32* __restrict__ RIDP,
  ushort_t* CaT, int NRE, int NQ)
{
  __shared__ float hrow[D];
  int d = threadIdx.x;
  int b = blockIdx.x;
  if (b < NRE) {
    const ushort_t* row = rela + (size_t)b*D;
    hrow[d] = bf2f(row[d]);
    __syncthreads();
    float az=0.f, ar=0.f, ah=0.f;
    for (int k=0;k<D;k++){
      float h = hrow[k];
      az += h*bf2f(Wz[k*D+d]);
      ar += h*bf2f(Wr[k*D+d]);
      ah += h*bf2f(Wh[k*D+d]);
    }
    float azn = __shfl_xor(az,1), arn = __shfl_xor(ar,1), ahn = __shfl_xor(ah,1);
    if (!(d & 1)){
      u32* out = RELP + (size_t)b*192 + (d>>1)*3;
      out[0] = packbf(az, azn); out[1] = packbf(ar, arn); out[2] = packbf(ah, ahn);
    }
  } else {
    int q = b - NRE; if (q >= NQ) return;
    int rq = q_rel[q];
    const ushort_t* row = rela + (size_t)rq*D;
    hrow[d] = bf2f(row[d]);
    hq_tab[q*D+d] = row[d];
    __syncthreads();
    float vz=bf2f(bz[d]), vr=bf2f(br[d]), vh=bf2f(bh[d]), vc=bf2f(bqr[d]);
    for (int k=0;k<D;k++){
      float h = hrow[k];
      vz += h*bf2f(Wz[(D+k)*D+d]);
      vr += h*bf2f(Wr[(D+k)*D+d]);
      vh += h*bf2f(Wh[(D+k)*D+d]);
      vc += h*bf2f(Wqr[k*D+d]);
    }
    float vzn = __shfl_xor(vz,1), vrn = __shfl_xor(vr,1), vhn = __shfl_xor(vh,1);
    if (!(d & 1)){
      u32* out = RIDP + (size_t)q*192 + (d>>1)*3;
      out[0] = packbf(vz, vzn); out[1] = packbf(vr, vrn); out[2] = packbf(vh, vhn);
    }
    CaT[q*D + (d&15)*8 + (d>>4)] = f2bf(vc);
  }
}

// ---------------- shared MFMA matvec helpers ----------------
// A in LDS: row e at e*256, cols 2l,2l+1 written at ((4*l)^((e&7)<<4)).
// B in LDS: transposed+swizzled, row (t*16+arow) at *256 + ((2k)^((row&7)<<4)).
__device__ __forceinline__ void matvec16(const char* vA_hi, const char* vA_lo,
                                         const char* Bm, int l, f32x4 acc[8])
{
  int arow = l & 15, agrp = l >> 4;
  int swz = (arow & 7) << 4;
  bf16x8 ah[4], al[4];
  #pragma unroll
  for (int kk=0; kk<4; kk++){
    int off = (kk*64 + agrp*16) ^ swz;
    ah[kk] = *(const bf16x8*)(vA_hi + arow*256 + off);
    al[kk] = *(const bf16x8*)(vA_lo + arow*256 + off);
  }
  #pragma unroll
  for (int t=0; t<8; t++){
    const char* bbase = Bm + (t*16 + arow)*256;
    #pragma unroll
    for (int kk=0; kk<4; kk++){
      bf16x8 bf = *(const bf16x8*)(bbase + ((kk*64 + agrp*16) ^ swz));
      acc[t] = __builtin_amdgcn_mfma_f32_16x16x32_bf16(ah[kk], bf, acc[t], 0,0,0);
      acc[t] = __builtin_amdgcn_mfma_f32_16x16x32_bf16(al[kk], bf, acc[t], 0,0,0);
    }
  }
}

// single-precision-A variant (A exact bf16, no hi/lo split)
__device__ __forceinline__ void matvec16s(const char* vA,
                                          const char* Bm, int l, f32x4 acc[8])
{
  int arow = l & 15, agrp = l >> 4;
  int swz = (arow & 7) << 4;
  bf16x8 ah[4];
  #pragma unroll
  for (int kk=0; kk<4; kk++){
    int off = (kk*64 + agrp*16) ^ swz;
    ah[kk] = *(const bf16x8*)(vA + arow*256 + off);
  }
  #pragma unroll
  for (int t=0; t<8; t++){
    const char* bbase = Bm + (t*16 + arow)*256;
    #pragma unroll
    for (int kk=0; kk<4; kk++){
      bf16x8 bf = *(const bf16x8*)(bbase + ((kk*64 + agrp*16) ^ swz));
      acc[t] = __builtin_amdgcn_mfma_f32_16x16x32_bf16(ah[kk], bf, acc[t], 0,0,0);
    }
  }
}

// ---------------- SUB3 via MFMA: {hidden@Uz, hidden@Ur, hidden} per node ------
// 768 thr / 12 waves; LDS = 64KB UzT/UrT + 8KB/wave = 160KB -> 3 waves/SIMD.
// amdgpu_waves_per_eu(3,3): dynamic-LDS size is invisible at compile time, so
// without the pin the allocator budgets for 6 waves/EU (VGPR 84) and spills
// ~300MB/dispatch of scratch (R10/R11: FETCH_SIZE 236->491MB).
#define HU_SMEM (65536 + 12*8192)   // 163840

__global__ __launch_bounds__(768)
__attribute__((amdgpu_waves_per_eu(3,3)))
void hu_kernel(
  const ushort_t* __restrict__ hidden,
  const ushort_t* __restrict__ Uz, const ushort_t* __restrict__ Ur,
  u32* __restrict__ SUB3, int N)
{
  extern __shared__ char smem[];
  int tid = threadIdx.x;
  int w = tid >> 6, l = tid & 63;

  for (int idx = tid; idx < 128*64; idx += 768) {
    int k  = idx >> 6;
    int cp = idx & 63;
    u32 wu = *(const u32*)(Uz + (size_t)k*D + 2*cp);
    u32 ww = *(const u32*)(Ur + (size_t)k*D + 2*cp);
    int r0 = 2*cp, r1 = 2*cp+1;
    int o0 = (2*k) ^ ((r0&7)<<4);
    int o1 = (2*k) ^ ((r1&7)<<4);
    *(ushort_t*)(smem + r0*256 + o0) = (ushort_t)(wu & 0xffffu);
    *(ushort_t*)(smem + r1*256 + o1) = (ushort_t)(wu >> 16);
    *(ushort_t*)(smem + 32768 + r0*256 + o0) = (ushort_t)(ww & 0xffffu);
    *(ushort_t*)(smem + 32768 + r1*256 + o1) = (ushort_t)(ww >> 16);
  }
  __syncthreads();

  char* vA  = smem + 65536 + w*8192;
  u32* accb = (u32*)vA;   // full 8KB reused as f32 transpose buffer
  int arow = l & 15, agrp = l >> 4;
  int c0 = 2*l;

  int nIter = (N + 191) / 192;
  for (int it = blockIdx.x; it < nIter; it += gridDim.x) {
    int base = it*192 + w*16;
    u32 hword[16];
    #pragma unroll
    for (int e=0;e<16;e++){
      int n = base + e; if (n >= N) n = N-1;
      u32 hw = *(const u32*)(hidden + (size_t)n*D + c0);
      hword[e] = hw;
      *(u32*)(vA + e*256 + ((4*l) ^ ((e&7)<<4))) = hw;
    }
    f32x4 az[8], ar[8];
    #pragma unroll
    for (int t=0;t<8;t++){ az[t]=(f32x4){0.f,0.f,0.f,0.f}; ar[t]=(f32x4){0.f,0.f,0.f,0.f}; }
    matvec16s(vA, smem, l, az);
    matvec16s(vA, smem + 32768, l, ar);

    // transpose az (C-layout -> phase-1 layout) through accb
    #pragma unroll
    for (int t=0;t<8;t++){
      #pragma unroll
      for (int r=0;r<4;r++){
        int e_ = agrp*4 + r;
        int c  = t*16 + arow;
        accb[e_*128 + (c ^ (agrp<<3))] = __float_as_uint(az[t][r]);
      }
    }
    float2 xz[16];
    #pragma unroll
    for (int e=0;e<16;e++)
      xz[e] = *(float2*)&accb[e*128 + ((2*l) ^ ((e>>2)<<3))];
    // transpose ar
    #pragma unroll
    for (int t=0;t<8;t++){
      #pragma unroll
      for (int r=0;r<4;r++){
        int e_ = agrp*4 + r;
        int c  = t*16 + arow;
        accb[e_*128 + (c ^ (agrp<<3))] = __float_as_uint(ar[t][r]);
      }
    }
    float2 xr[16];
    #pragma unroll
    for (int e=0;e<16;e++)
      xr[e] = *(float2*)&accb[e*128 + ((2*l) ^ ((e>>2)<<3))];

    #pragma unroll
    for (int e=0;e<16;e++){
      int n = base + e;
      if (n < N){
        u32* out = SUB3 + (size_t)n*192 + l*3;
        out[0] = packbf(xz[e].x, xz[e].y);
        out[1] = packbf(xr[e].x, xr[e].y);
        out[2] = hword[e];
      }
    }
  }
}

// ================= MFMA edge kernel: lean body @ 3 waves/SIMD ================
// 768-thread block, 12 waves, 16 edges/wave, 192 edges/block-iter.
// LDS: 64KB swizzled UhT/WsT + 8KB/wave vA = 160KB (full CU LDS) ->
// 1 block/CU = 12 waves/CU = 3 waves/SIMD.
// amdgpu_waves_per_eu(3,3) pins the VGPR budget to 512/3=170 (see hu_kernel).
#define SMEM_WST 32768
#define SMEM_VA  65536
#define EDGE_SMEM (65536 + 12*8192)   // 163840

__global__ __launch_bounds__(768)
__attribute__((amdgpu_waves_per_eu(3,3)))
void edge_kernel(
  const int* __restrict__ edges,
  const u32* __restrict__ SUB3, const u32* __restrict__ RELP, const u32* __restrict__ RIDP,
  const ushort_t* __restrict__ CaT,
  const ushort_t* __restrict__ Uh, const ushort_t* __restrict__ Ws,
  const ushort_t* __restrict__ w_alpha, const ushort_t* __restrict__ b_alpha,
  ushort_t* __restrict__ aggh, float* __restrict__ sum_exp, int* __restrict__ last_edge,
  int E)
{
  extern __shared__ char smem[];
  int tid = threadIdx.x;
  int w = tid >> 6, l = tid & 63;

  // stage Uh^T, Ws^T into LDS with XOR swizzle: M_T[r][k] at r*256 + ((2k)^((r&7)<<4))
  for (int idx = tid; idx < 128*64; idx += 768) {
    int k  = idx >> 6;
    int cp = idx & 63;
    u32 wu = *(const u32*)(Uh + (size_t)k*D + 2*cp);
    u32 ww = *(const u32*)(Ws + (size_t)k*D + 2*cp);
    int r0 = 2*cp, r1 = 2*cp+1;
    int o0 = (2*k) ^ ((r0&7)<<4);
    int o1 = (2*k) ^ ((r1&7)<<4);
    *(ushort_t*)(smem + r0*256 + o0) = (ushort_t)(wu & 0xffffu);
    *(ushort_t*)(smem + r1*256 + o1) = (ushort_t)(wu >> 16);
    *(ushort_t*)(smem + SMEM_WST + r0*256 + o0) = (ushort_t)(ww & 0xffffu);
    *(ushort_t*)(smem + SMEM_WST + r1*256 + o1) = (ushort_t)(ww >> 16);
  }
  __syncthreads();

  char* vA_hi = smem + SMEM_VA + w*8192;
  char* vA_lo = vA_hi + 4096;
  u32*  accb  = (u32*)vA_hi;   // same 8KB, time-shared as f32 transpose buffer

  int arow = l & 15, agrp = l >> 4;
  float wal[8];
  #pragma unroll
  for (int t=0; t<8; t++) wal[t] = bf2f(w_alpha[t*16 + arow]);
  float bal = bf2f(b_alpha[0]);
  int c0 = 2*l;

  int nIter = (E + 191) / 192;
  for (int it = blockIdx.x; it < nIter; it += gridDim.x) {
    int eb = it*192 + w*16;

    // meta: lane (l&15) owns edge eb+(l&15)
    int myE = eb + arow; if (myE >= E) myE = E - 1;
    const int* ep = edges + (size_t)myE*6;
    int v_ridx = ep[0];
    int v_rel  = ep[2];
    int v_sub  = ep[4];
    int v_obj  = ep[5];

    // ---- phase 1: gate z,r ; v = r*h_s ; keep z/hs/(Ah+Bh) in regs ----
    u32 zpk[16], hwd[16], acp[16];
    #pragma unroll
    for (int e=0; e<16; e++){
      int rel = __shfl(v_rel, e);
      int rid = __shfl(v_ridx, e);
      int sub = __shfl(v_sub, e);
      uint3 rp = *(const uint3*)(RELP + (size_t)rel*192 + l*3);
      uint3 qp = *(const uint3*)(RIDP + (size_t)rid*192 + l*3);
      uint3 sp = *(const uint3*)(SUB3 + (size_t)sub*192 + l*3);
      float2 az = bfp2(rp.x), ar = bfp2(rp.y), ah = bfp2(rp.z);
      float2 bz = bfp2(qp.x), br = bfp2(qp.y), bh = bfp2(qp.z);
      float2 hz = bfp2(sp.x), hr = bfp2(sp.y), hs = bfp2(sp.z);
      float z0 = sigm(az.x+bz.x+hz.x), z1 = sigm(az.y+bz.y+hz.y);
      float r0 = sigm(ar.x+br.x+hr.x), r1 = sigm(ar.y+br.y+hr.y);
      float v0 = r0*hs.x, v1 = r1*hs.y;
      // hi = truncated bf16, lo = RNE(residual): vh+vl == v to ~2^-17
      u32 u0 = __float_as_uint(v0), u1 = __float_as_uint(v1);
      u32 whi = (u0 >> 16) | (u1 & 0xffff0000u);
      float vl0 = v0 - __uint_as_float(u0 & 0xffff0000u);
      float vl1 = v1 - __uint_as_float(u1 & 0xffff0000u);
      int voff = e*256 + ((4*l) ^ ((e&7)<<4));
      *(u32*)(vA_hi + voff) = whi;
      *(u32*)(vA_lo + voff) = cvtpk(vl0, vl1);
      zpk[e] = cvtpk(z0, z1);
      hwd[e] = sp.z;
      acp[e] = cvtpk(ah.x+bh.x, ah.y+bh.y);
    }

    // ---- phase 2: acc = v @ Uh ----
    f32x4 acc[8];
    #pragma unroll
    for (int t=0; t<8; t++) acc[t] = (f32x4){0.f,0.f,0.f,0.f};
    matvec16(vA_hi, vA_lo, smem, l, acc);

    // ---- phase 3a: transpose acc (C-layout) -> accb f32, swizzled ----
    #pragma unroll
    for (int t=0; t<8; t++){
      #pragma unroll
      for (int r=0; r<4; r++){
        int e_ = agrp*4 + r;
        int c  = t*16 + arow;
        accb[e_*128 + (c ^ (agrp<<3))] = __float_as_uint(acc[t][r]);
      }
    }
    // ---- phase 3b: read back in phase-1 layout (ALL reads before any write) ----
    float2 xv[16];
    #pragma unroll
    for (int e=0; e<16; e++)
      xv[e] = *(float2*)&accb[e*128 + ((2*l) ^ ((e>>2)<<3))];

    // ---- phase 3c: ht = tanh(acc + Ah+Bh); m = (1-z)hs + z ht ; m -> vA ----
    float mf0[16], mf1[16];
    #pragma unroll
    for (int e=0; e<16; e++){
      float2 ac = bfp2(acp[e]);
      float2 zh = bfp2(zpk[e]);
      float2 hs = bfp2(hwd[e]);
      float ht0 = ftanh(xv[e].x + ac.x);
      float ht1 = ftanh(xv[e].y + ac.y);
      float m0 = (1.0f - zh.x)*hs.x + zh.x*ht0;
      float m1 = (1.0f - zh.y)*hs.y + zh.y*ht1;
      mf0[e] = m0; mf1[e] = m1;
      u32 u0 = __float_as_uint(m0), u1 = __float_as_uint(m1);
      u32 whi = (u0 >> 16) | (u1 & 0xffff0000u);
      float vl0 = m0 - __uint_as_float(u0 & 0xffff0000u);
      float vl1 = m1 - __uint_as_float(u1 & 0xffff0000u);
      int voff = e*256 + ((4*l) ^ ((e&7)<<4));
      *(u32*)(vA_hi + voff) = whi;
      *(u32*)(vA_lo + voff) = cvtpk(vl0, vl1);
    }

    // ---- phase 4: a2 = m @ Ws ----
    f32x4 a2[8];
    #pragma unroll
    for (int t=0; t<8; t++) a2[t] = (f32x4){0.f,0.f,0.f,0.f};
    matvec16(vA_hi, vA_lo, smem + SMEM_WST, l, a2);

    // ---- phase 5: attention scores (C-layout); CaT packed 16B/lane ----
    float ea[4];
    #pragma unroll
    for (int r=0; r<4; r++){
      int rid_r = __shfl(v_ridx, agrp*4 + r);
      uint4 cw = *(const uint4*)(CaT + (size_t)rid_r*D + arow*8);
      float2 c01 = bfp2(cw.x), c23 = bfp2(cw.y), c45 = bfp2(cw.z), c67 = bfp2(cw.w);
      float s = 0.f;
      s += fmaxf(a2[0][r]+c01.x,0.f)*wal[0];
      s += fmaxf(a2[1][r]+c01.y,0.f)*wal[1];
      s += fmaxf(a2[2][r]+c23.x,0.f)*wal[2];
      s += fmaxf(a2[3][r]+c23.y,0.f)*wal[3];
      s += fmaxf(a2[4][r]+c45.x,0.f)*wal[4];
      s += fmaxf(a2[5][r]+c45.y,0.f)*wal[5];
      s += fmaxf(a2[6][r]+c67.x,0.f)*wal[6];
      s += fmaxf(a2[7][r]+c67.y,0.f)*wal[7];
      s += __shfl_xor(s, 1); s += __shfl_xor(s, 2);
      s += __shfl_xor(s, 4); s += __shfl_xor(s, 8);
      ea[r] = __expf(s + bal);
    }

    // ---- phase 6: one pk atomic per edge = full 256B contiguous agg row ----
    #pragma unroll
    for (int e=0; e<16; e++){
      float ea_e = __shfl(ea[e & 3], (e >> 2) << 4);
      int obj_e  = __shfl(v_obj, e);
      int eg = eb + e;
      if (eg < E)
        atompk(aggh + (size_t)obj_e*D + c0, cvtpk(ea_e*mf0[e], ea_e*mf1[e]));
    }
    // batched tail: lane arow (group 0) handles edge eb+arow in ONE atomic pair
    {
      int srcl = (arow >> 2) << 4;
      float s0 = __shfl(ea[0], srcl);
      float s1 = __shfl(ea[1], srcl);
      float s2 = __shfl(ea[2], srcl);
      float s3 = __shfl(ea[3], srcl);
      int rr = arow & 3;
      float eav = (rr == 0) ? s0 : (rr == 1) ? s1 : (rr == 2) ? s2 : s3;
      if (agrp == 0 && (eb + arow) < E){
        atomicAdd(sum_exp + v_obj, eav);
        atomicMax(last_edge + v_obj, eb + arow);
      }
    }
  }
}

// ---------------- finalize (4-node batched, dual output format) ----------------
__global__ __launch_bounds__(256) void final_kernel(
  const ushort_t* __restrict__ aggh, const float* __restrict__ sum_exp,
  const int* __restrict__ last_edge, const int* __restrict__ edges,
  const ushort_t* __restrict__ hq_tab, const ushort_t* __restrict__ Wh,
  const int* __restrict__ flag, void* __restrict__ out_base, int N)
{
  __shared__ float mb[4][D][4];
  int tid = threadIdx.x, w = tid >> 6, l = tid & 63;
  int c0 = 2*l, c1 = c0+1;
  int isf = *flag;
  float* out0f = (float*)out_base;
  float* out1f = out0f + (size_t)N*D;
  ushort_t* out0h = (ushort_t*)out_base;
  ushort_t* out1h = out0h + (size_t)N*D;
  int nIter = (N + 15) >> 4;
  for (int it = blockIdx.x; it < nIter; it += gridDim.x){
    int base = it*16 + w*4;
    int rq[4];
    #pragma unroll
    for (int e=0;e<4;e++){
      int n = base + e; if (n >= N) n = N-1;
      float se = sum_exp[n];
      float inv = (se > 0.f) ? (1.0f/se) : 0.f;
      float2 m = bfp2(*(const u32*)(aggh + (size_t)n*D + c0));
      mb[w][c0][e] = m.x*inv; mb[w][c1][e] = m.y*inv;
      int le = last_edge[n];
      rq[e] = (le >= 0) ? edges[(size_t)le*6] : 0;
    }
    float a0[4] = {0,0,0,0}, a1[4] = {0,0,0,0};
    #pragma unroll 4
    for (int kp=0; kp<64; kp++){
      float4 ma = *(float4*)&mb[w][2*kp][0];
      float4 mv = *(float4*)&mb[w][2*kp+1][0];
      float2 u0 = bfp2(*(const u32*)(Wh + (2*kp)*D + c0));
      float2 u1 = bfp2(*(const u32*)(Wh + (2*kp+1)*D + c0));
      a0[0] += ma.x*u0.x + mv.x*u1.x;  a1[0] += ma.x*u0.y + mv.x*u1.y;
      a0[1] += ma.y*u0.x + mv.y*u1.x;  a1[1] += ma.y*u0.y + mv.y*u1.y;
      a0[2] += ma.z*u0.x + mv.z*u1.x;  a1[2] += ma.z*u0.y + mv.z*u1.y;
      a0[3] += ma.w*u0.x + mv.w*u1.x;  a1[3] += ma.w*u0.y + mv.w*u1.y;
    }
    #pragma unroll
    for (int e=0;e<4;e++){
      int n = base + e; if (n >= N) continue;
      float r0 = fmaxf(a0[e], 0.f), r1 = fmaxf(a1[e], 0.f);
      u32 hqw = *(const u32*)(hq_tab + (size_t)rq[e]*D + c0);
      if (isf){
        float2 o0; o0.x = r0; o0.y = r1;
        *(float2*)(out0f + (size_t)n*D + c0) = o0;
        float2 hv = bfp2(hqw);
        *(float2*)(out1f + (size_t)n*D + c0) = hv;
      } else {
        *(u32*)(out0h + (size_t)n*D + c0) = packbf(r0, r1);
        *(u32*)(out1h + (size_t)n*D + c0) = hqw;
      }
    }
  }
}

extern "C" void kernel_launch(void* const* d_in, const int* in_sizes, int n_in,
                              void* d_out, int out_size, void* d_ws, size_t ws_size,
                              hipStream_t stream)
{
  const int* q_rel = (const int*)d_in[17];
  const int* edges = (const int*)d_in[18];

  int N   = in_sizes[0]/D;
  int NRE = in_sizes[1]/D;
  int NQ  = in_sizes[17];
  int E   = in_sizes[18]/6;

  char* ws = (char*)d_ws;
  size_t o = 0;
  auto alloc = [&](size_t bytes)->void*{
    void* p = ws + o; o += (bytes + 255) & ~(size_t)255; return p;
  };
  ushort_t* aggh  = (ushort_t*)alloc((size_t)N*D*2);
  float* sum_exp  = (float*)alloc((size_t)N*4);
  int*   lastedge = (int*)  alloc((size_t)N*4);
  int*   flag     = (int*)  alloc(256);

  ushort_t* canon[17];
  for (int i=0;i<17;i++) canon[i] = (ushort_t*)alloc((size_t)in_sizes[i]*2);

  ushort_t* hq_tab = (ushort_t*)alloc((size_t)NQ*D*2);
  ushort_t* CaT = (ushort_t*)alloc((size_t)NQ*D*2);
  u32* RELP = (u32*)alloc((size_t)NRE*192*4);
  u32* RIDP = (u32*)alloc((size_t)NQ*192*4);
  u32* SUB3 = (u32*)alloc((size_t)N*192*4);

  CvtArgs ca;
  for (int i=0;i<17;i++){ ca.src[i]=d_in[i]; ca.dst[i]=canon[i]; ca.n[i]=in_sizes[i]; }

  const ushort_t* hidden = canon[0];
  const ushort_t* rela   = canon[1];
  const ushort_t* Wz  = canon[2];
  const ushort_t* Uz  = canon[3];
  const ushort_t* bz  = canon[4];
  const ushort_t* Wr  = canon[5];
  const ushort_t* Ur  = canon[6];
  const ushort_t* br  = canon[7];
  const ushort_t* Whh = canon[8];
  const ushort_t* Uh  = canon[9];
  const ushort_t* bh  = canon[10];
  const ushort_t* Ws  = canon[11];
  const ushort_t* Wqr = canon[12];
  const ushort_t* bqr = canon[13];
  const ushort_t* wal = canon[14];
  const ushort_t* bal = canon[15];
  const ushort_t* W_h = canon[16];

  convert_kernel<<<1024, 256, 0, stream>>>(ca, (const u32*)d_in[1], flag,
                                           (u32*)aggh, sum_exp, lastedge, N);
  table_kernel<<<NRE+NQ, 128, 0, stream>>>(rela, Wz, Wr, Whh, Wqr, bz, br, bh, bqr,
                                           q_rel, hq_tab, RELP, RIDP, CaT, NRE, NQ);

  hipFuncSetAttribute(reinterpret_cast<const void*>(hu_kernel),
                      hipFuncAttributeMaxDynamicSharedMemorySize, HU_SMEM);
  hu_kernel<<<256, 768, HU_SMEM, stream>>>(hidden, Uz, Ur, SUB3, N);

  hipFuncSetAttribute(reinterpret_cast<const void*>(edge_kernel),
                      hipFuncAttributeMaxDynamicSharedMemorySize, EDGE_SMEM);
  edge_kernel<<<256, 768, EDGE_SMEM, stream>>>(edges, SUB3, RELP, RIDP, CaT,
                                               Uh, Ws, wal, bal, aggh, sum_exp, lastedge, E);
  final_kernel<<<1024, 256, 0, stream>>>(aggh, sum_exp, lastedge, edges, hq_tab, W_h,
                                         flag, d_out, N);
}

// Round 14
// 614.289 us; speedup vs baseline: 1.0501x; 1.0501x over previous
//
#include <hip/hip_runtime.h>
#include <hip/hip_bf16.h>

#define D 128

typedef unsigned int u32;
typedef unsigned short ushort_t;

typedef __attribute__((ext_vector_type(8))) __bf16 bf16x8;
typedef __attribute__((ext_vector_type(4))) float f32x4;

__device__ __forceinline__ float bf2f(ushort_t u){ return __uint_as_float(((u32)u)<<16); }
__device__ __forceinline__ ushort_t f2bf(float f){
  u32 x = __float_as_uint(f);
  return (ushort_t)((x + 0x7fffu + ((x>>16)&1u)) >> 16);
}
// packed dword = two consecutive bf16 elements (lo = even col, hi = odd col)
__device__ __forceinline__ float2 bfp2(u32 w){
  float2 r; r.x = __uint_as_float(w<<16); r.y = __uint_as_float(w & 0xffff0000u); return r;
}
__device__ __forceinline__ u32 packbf(float a, float b){
  return (u32)f2bf(a) | ((u32)f2bf(b)<<16);
}
// hardware packed f32->bf16 (RNE): lo = bf16(a), hi = bf16(b)
__device__ __forceinline__ u32 cvtpk(float a, float b){
  u32 r; asm("v_cvt_pk_bf16_f32 %0, %1, %2" : "=v"(r) : "v"(a), "v"(b)); return r;
}
__device__ __forceinline__ ushort_t cvt1(float a){
  u32 r; asm("v_cvt_pk_bf16_f32 %0, %1, %1" : "=v"(r) : "v"(a)); return (ushort_t)r;
}
// packed bf16 atomic add (gfx940+): one dword = 2 consecutive bf16 elements
__device__ __forceinline__ void atompk(ushort_t* p, u32 v){
  asm volatile("global_atomic_pk_add_bf16 %0, %1, off" :: "v"(p), "v"(v) : "memory");
}
__device__ __forceinline__ float sigm(float x){ return 1.0f/(1.0f+__expf(-x)); }
__device__ __forceinline__ float ftanh(float x){
  float e = __expf(-2.0f*fabsf(x));
  float t = (1.0f-e)/(1.0f+e);
  return copysignf(t,x);
}

// ---------------- fused convert + dtype-detect + init ----------------
struct CvtArgs { const void* src[17]; ushort_t* dst[17]; int n[17]; };

__global__ __launch_bounds__(256) void convert_kernel(CvtArgs a,
  const u32* __restrict__ probe, int* __restrict__ flag,
  u32* __restrict__ aggz, float* __restrict__ sum_exp, int* __restrict__ last_edge, int N)
{
  __shared__ int s_isf;
  int tid = threadIdx.x;
  if (tid < 64){
    int cnt = 0;
    for (int i = tid; i < 512; i += 64){
      u32 w = probe[i];
      u32 e = (w >> 7) & 0xFFu;
      if (e >= 100u && e <= 126u) cnt++;
    }
    #pragma unroll
    for (int off = 32; off > 0; off >>= 1) cnt += __shfl_xor(cnt, off);
    if (tid == 0){
      s_isf = (cnt < 256) ? 1 : 0;
      if (blockIdx.x == 0) *flag = s_isf;
    }
  }
  __syncthreads();
  int isf = s_isf;
  int gid = blockIdx.x*blockDim.x + tid;
  int gs  = gridDim.x*blockDim.x;
  for (int s = 0; s < 17; s++){
    int n = a.n[s];
    ushort_t* dst = a.dst[s];
    int n4 = n >> 2;
    if (isf){
      const float4* src4 = (const float4*)a.src[s];
      uint2* dst4 = (uint2*)dst;
      for (int j = gid; j < n4; j += gs){
        float4 v = src4[j];
        uint2 o; o.x = packbf(v.x, v.y); o.y = packbf(v.z, v.w);
        dst4[j] = o;
      }
      const float* src = (const float*)a.src[s];
      for (int j = (n4<<2) + gid; j < n; j += gs) dst[j] = f2bf(src[j]);
    } else {
      const uint2* src4 = (const uint2*)a.src[s];
      uint2* dst4 = (uint2*)dst;
      for (int j = gid; j < n4; j += gs) dst4[j] = src4[j];
      const ushort_t* src = (const ushort_t*)a.src[s];
      for (int j = (n4<<2) + gid; j < n; j += gs) dst[j] = src[j];
    }
  }
  // init: agg (bf16) zero, sum_exp, last_edge
  int na = N*D/2;
  int na4 = na >> 2;
  uint4 z4 = make_uint4(0,0,0,0);
  for (int j=gid; j<na4; j+=gs) ((uint4*)aggz)[j] = z4;
  for (int j=(na4<<2)+gid; j<na; j+=gs) aggz[j]=0u;
  for (int j=gid; j<N;  j+=gs){ sum_exp[j]=0.f; last_edge[j]=-1; }
}

// ---------------- per-rel and per-query tables (packed triples) ----------------
// RELP[rel][64] = uint3 { (Az0,Az1), (Ar0,Ar1), (Ah0,Ah1) }  per col-pair
// RIDP[q  ][64] = uint3 { (Bz0,Bz1), (Br0,Br1), (Bh0,Bh1) }
// CaT[q][arow*8+t] = Ca[q][t*16+arow]  (C-layout order: 16B/lane in phase 5)
__global__ void table_kernel(const ushort_t* __restrict__ rela,
  const ushort_t* __restrict__ Wz, const ushort_t* __restrict__ Wr, const ushort_t* __restrict__ Wh,
  const ushort_t* __restrict__ Wqr,
  const ushort_t* __restrict__ bz, const ushort_t* __restrict__ br, const ushort_t* __restrict__ bh,
  const ushort_t* __restrict__ bqr,
  const int* __restrict__ q_rel,
  ushort_t* hq_tab, u32* __restrict__ RELP, u32* __restrict__ RIDP,
  ushort_t* CaT, int NRE, int NQ)
{
  __shared__ float hrow[D];
  int d = threadIdx.x;
  int b = blockIdx.x;
  if (b < NRE) {
    const ushort_t* row = rela + (size_t)b*D;
    hrow[d] = bf2f(row[d]);
    __syncthreads();
    float az=0.f, ar=0.f, ah=0.f;
    for (int k=0;k<D;k++){
      float h = hrow[k];
      az += h*bf2f(Wz[k*D+d]);
      ar += h*bf2f(Wr[k*D+d]);
      ah += h*bf2f(Wh[k*D+d]);
    }
    float azn = __shfl_xor(az,1), arn = __shfl_xor(ar,1), ahn = __shfl_xor(ah,1);
    if (!(d & 1)){
      u32* out = RELP + (size_t)b*192 + (d>>1)*3;
      out[0] = packbf(az, azn); out[1] = packbf(ar, arn); out[2] = packbf(ah, ahn);
    }
  } else {
    int q = b - NRE; if (q >= NQ) return;
    int rq = q_rel[q];
    const ushort_t* row = rela + (size_t)rq*D;
    hrow[d] = bf2f(row[d]);
    hq_tab[q*D+d] = row[d];
    __syncthreads();
    float vz=bf2f(bz[d]), vr=bf2f(br[d]), vh=bf2f(bh[d]), vc=bf2f(bqr[d]);
    for (int k=0;k<D;k++){
      float h = hrow[k];
      vz += h*bf2f(Wz[(D+k)*D+d]);
      vr += h*bf2f(Wr[(D+k)*D+d]);
      vh += h*bf2f(Wh[(D+k)*D+d]);
      vc += h*bf2f(Wqr[k*D+d]);
    }
    float vzn = __shfl_xor(vz,1), vrn = __shfl_xor(vr,1), vhn = __shfl_xor(vh,1);
    if (!(d & 1)){
      u32* out = RIDP + (size_t)q*192 + (d>>1)*3;
      out[0] = packbf(vz, vzn); out[1] = packbf(vr, vrn); out[2] = packbf(vh, vhn);
    }
    CaT[q*D + (d&15)*8 + (d>>4)] = f2bf(vc);
  }
}

// ---------------- shared MFMA matvec helpers ----------------
// A in LDS: row e at e*256, cols 2l,2l+1 written at ((4*l)^((e&7)<<4)).
// B in LDS: transposed+swizzled, row (t*16+arow) at *256 + ((2k)^((row&7)<<4)).
__device__ __forceinline__ void matvec16(const char* vA_hi, const char* vA_lo,
                                         const char* Bm, int l, f32x4 acc[8])
{
  int arow = l & 15, agrp = l >> 4;
  int swz = (arow & 7) << 4;
  bf16x8 ah[4], al[4];
  #pragma unroll
  for (int kk=0; kk<4; kk++){
    int off = (kk*64 + agrp*16) ^ swz;
    ah[kk] = *(const bf16x8*)(vA_hi + arow*256 + off);
    al[kk] = *(const bf16x8*)(vA_lo + arow*256 + off);
  }
  #pragma unroll
  for (int t=0; t<8; t++){
    const char* bbase = Bm + (t*16 + arow)*256;
    #pragma unroll
    for (int kk=0; kk<4; kk++){
      bf16x8 bf = *(const bf16x8*)(bbase + ((kk*64 + agrp*16) ^ swz));
      acc[t] = __builtin_amdgcn_mfma_f32_16x16x32_bf16(ah[kk], bf, acc[t], 0,0,0);
      acc[t] = __builtin_amdgcn_mfma_f32_16x16x32_bf16(al[kk], bf, acc[t], 0,0,0);
    }
  }
}

// single-precision-A variant (A exact bf16, no hi/lo split)
__device__ __forceinline__ void matvec16s(const char* vA,
                                          const char* Bm, int l, f32x4 acc[8])
{
  int arow = l & 15, agrp = l >> 4;
  int swz = (arow & 7) << 4;
  bf16x8 ah[4];
  #pragma unroll
  for (int kk=0; kk<4; kk++){
    int off = (kk*64 + agrp*16) ^ swz;
    ah[kk] = *(const bf16x8*)(vA + arow*256 + off);
  }
  #pragma unroll
  for (int t=0; t<8; t++){
    const char* bbase = Bm + (t*16 + arow)*256;
    #pragma unroll
    for (int kk=0; kk<4; kk++){
      bf16x8 bf = *(const bf16x8*)(bbase + ((kk*64 + agrp*16) ^ swz));
      acc[t] = __builtin_amdgcn_mfma_f32_16x16x32_bf16(ah[kk], bf, acc[t], 0,0,0);
    }
  }
}

// ---------------- SUB3 via MFMA: {hidden@Uz, hidden@Ur, hidden} per node ------
// R9-verified shape: 512 thr / 8 waves; LDS = 64KB UzT/UrT + 8KB/wave = 128KB
// -> 1 block/CU = 2 waves/SIMD, VGPR fits, no spill.
#define HU_SMEM (65536 + 8*8192)   // 131072

__global__ __launch_bounds__(512, 2) void hu_kernel(
  const ushort_t* __restrict__ hidden,
  const ushort_t* __restrict__ Uz, const ushort_t* __restrict__ Ur,
  u32* __restrict__ SUB3, int N)
{
  extern __shared__ char smem[];
  int tid = threadIdx.x;
  int w = tid >> 6, l = tid & 63;

  for (int idx = tid; idx < 128*64; idx += 512) {
    int k  = idx >> 6;
    int cp = idx & 63;
    u32 wu = *(const u32*)(Uz + (size_t)k*D + 2*cp);
    u32 ww = *(const u32*)(Ur + (size_t)k*D + 2*cp);
    int r0 = 2*cp, r1 = 2*cp+1;
    int o0 = (2*k) ^ ((r0&7)<<4);
    int o1 = (2*k) ^ ((r1&7)<<4);
    *(ushort_t*)(smem + r0*256 + o0) = (ushort_t)(wu & 0xffffu);
    *(ushort_t*)(smem + r1*256 + o1) = (ushort_t)(wu >> 16);
    *(ushort_t*)(smem + 32768 + r0*256 + o0) = (ushort_t)(ww & 0xffffu);
    *(ushort_t*)(smem + 32768 + r1*256 + o1) = (ushort_t)(ww >> 16);
  }
  __syncthreads();

  char* vA  = smem + 65536 + w*8192;
  u32* accb = (u32*)vA;   // full 8KB reused as f32 transpose buffer
  int arow = l & 15, agrp = l >> 4;
  int c0 = 2*l;

  int nIter = (N + 127) >> 7;
  for (int it = blockIdx.x; it < nIter; it += gridDim.x) {
    int base = it*128 + w*16;
    u32 hword[16];
    #pragma unroll
    for (int e=0;e<16;e++){
      int n = base + e; if (n >= N) n = N-1;
      u32 hw = *(const u32*)(hidden + (size_t)n*D + c0);
      hword[e] = hw;
      *(u32*)(vA + e*256 + ((4*l) ^ ((e&7)<<4))) = hw;
    }
    f32x4 az[8], ar[8];
    #pragma unroll
    for (int t=0;t<8;t++){ az[t]=(f32x4){0.f,0.f,0.f,0.f}; ar[t]=(f32x4){0.f,0.f,0.f,0.f}; }
    matvec16s(vA, smem, l, az);
    matvec16s(vA, smem + 32768, l, ar);

    // transpose az (C-layout -> phase-1 layout) through accb
    #pragma unroll
    for (int t=0;t<8;t++){
      #pragma unroll
      for (int r=0;r<4;r++){
        int e_ = agrp*4 + r;
        int c  = t*16 + arow;
        accb[e_*128 + (c ^ (agrp<<3))] = __float_as_uint(az[t][r]);
      }
    }
    float2 xz[16];
    #pragma unroll
    for (int e=0;e<16;e++)
      xz[e] = *(float2*)&accb[e*128 + ((2*l) ^ ((e>>2)<<3))];
    // transpose ar
    #pragma unroll
    for (int t=0;t<8;t++){
      #pragma unroll
      for (int r=0;r<4;r++){
        int e_ = agrp*4 + r;
        int c  = t*16 + arow;
        accb[e_*128 + (c ^ (agrp<<3))] = __float_as_uint(ar[t][r]);
      }
    }
    float2 xr[16];
    #pragma unroll
    for (int e=0;e<16;e++)
      xr[e] = *(float2*)&accb[e*128 + ((2*l) ^ ((e>>2)<<3))];

    #pragma unroll
    for (int e=0;e<16;e++){
      int n = base + e;
      if (n < N){
        u32* out = SUB3 + (size_t)n*192 + l*3;
        out[0] = packbf(xz[e].x, xz[e].y);
        out[1] = packbf(xr[e].x, xr[e].y);
        out[2] = hword[e];
      }
    }
  }
}

// ================= MFMA edge kernel: R9 shape + depth-1 meta prefetch ========
// 512-thread block, 8 waves, 16 edges/wave, 128 edges/block-iter.
// LDS: 64KB swizzled UhT/WsT + 8KB/wave vA = 128KB -> 1 block/CU = 2 waves/SIMD.
// (768-thread/160KB shape abandoned: dynamic-LDS occupancy is invisible to the
// register allocator -> it budgets 84 VGPR for 2 blocks/CU and spills ~300MB
// per dispatch; R10-R12 all landed at 438-440us = no better than this shape.)
// New: next-iteration edge META (4 ints/lane) prefetched in registers -- the
// meta load heads the iteration's serial dependency chain (meta->shfl->gather).
#define SMEM_WST 32768
#define SMEM_VA  65536
#define EDGE_SMEM (65536 + 8*8192)   // 131072

__global__ __launch_bounds__(512, 2) void edge_kernel(
  const int* __restrict__ edges,
  const u32* __restrict__ SUB3, const u32* __restrict__ RELP, const u32* __restrict__ RIDP,
  const ushort_t* __restrict__ CaT,
  const ushort_t* __restrict__ Uh, const ushort_t* __restrict__ Ws,
  const ushort_t* __restrict__ w_alpha, const ushort_t* __restrict__ b_alpha,
  ushort_t* __restrict__ aggh, float* __restrict__ sum_exp, int* __restrict__ last_edge,
  int E)
{
  extern __shared__ char smem[];
  int tid = threadIdx.x;
  int w = tid >> 6, l = tid & 63;

  // stage Uh^T, Ws^T into LDS with XOR swizzle: M_T[r][k] at r*256 + ((2k)^((r&7)<<4))
  for (int idx = tid; idx < 128*64; idx += 512) {
    int k  = idx >> 6;
    int cp = idx & 63;
    u32 wu = *(const u32*)(Uh + (size_t)k*D + 2*cp);
    u32 ww = *(const u32*)(Ws + (size_t)k*D + 2*cp);
    int r0 = 2*cp, r1 = 2*cp+1;
    int o0 = (2*k) ^ ((r0&7)<<4);
    int o1 = (2*k) ^ ((r1&7)<<4);
    *(ushort_t*)(smem + r0*256 + o0) = (ushort_t)(wu & 0xffffu);
    *(ushort_t*)(smem + r1*256 + o1) = (ushort_t)(wu >> 16);
    *(ushort_t*)(smem + SMEM_WST + r0*256 + o0) = (ushort_t)(ww & 0xffffu);
    *(ushort_t*)(smem + SMEM_WST + r1*256 + o1) = (ushort_t)(ww >> 16);
  }
  __syncthreads();

  char* vA_hi = smem + SMEM_VA + w*8192;
  char* vA_lo = vA_hi + 4096;
  u32*  accb  = (u32*)vA_hi;   // same 8KB, time-shared as f32 transpose buffer

  int arow = l & 15, agrp = l >> 4;
  float wal[8];
  #pragma unroll
  for (int t=0; t<8; t++) wal[t] = bf2f(w_alpha[t*16 + arow]);
  float bal = bf2f(b_alpha[0]);
  int c0 = 2*l;

  int nIter = (E + 127) >> 7;
  int stride = gridDim.x;
  int it = blockIdx.x;
  if (it >= nIter) return;

  // prologue: meta for first iteration
  int myE = it*128 + w*16 + arow; if (myE >= E) myE = E - 1;
  const int* ep = edges + (size_t)myE*6;
  int v_ridx = ep[0];
  int v_rel  = ep[2];
  int v_sub  = ep[4];
  int v_obj  = ep[5];

  while (true) {
    int eb = it*128 + w*16;
    int itn = it + stride;

    // ---- prefetch next iteration's meta (clamped -> always-safe load) ----
    int nxE = itn*128 + w*16 + arow; if (nxE >= E) nxE = E - 1;
    const int* np = edges + (size_t)nxE*6;
    int n_ridx = np[0];
    int n_rel  = np[2];
    int n_sub  = np[4];
    int n_obj  = np[5];

    // ---- phase 1: gate z,r ; v = r*h_s ; keep z/hs/(Ah+Bh) in regs ----
    u32 zpk[16], hwd[16], acp[16];
    #pragma unroll
    for (int e=0; e<16; e++){
      int rel = __shfl(v_rel, e);
      int rid = __shfl(v_ridx, e);
      int sub = __shfl(v_sub, e);
      uint3 rp = *(const uint3*)(RELP + (size_t)rel*192 + l*3);
      uint3 qp = *(const uint3*)(RIDP + (size_t)rid*192 + l*3);
      uint3 sp = *(const uint3*)(SUB3 + (size_t)sub*192 + l*3);
      float2 az = bfp2(rp.x), ar = bfp2(rp.y), ah = bfp2(rp.z);
      float2 bz = bfp2(qp.x), br = bfp2(qp.y), bh = bfp2(qp.z);
      float2 hz = bfp2(sp.x), hr = bfp2(sp.y), hs = bfp2(sp.z);
      float z0 = sigm(az.x+bz.x+hz.x), z1 = sigm(az.y+bz.y+hz.y);
      float r0 = sigm(ar.x+br.x+hr.x), r1 = sigm(ar.y+br.y+hr.y);
      float v0 = r0*hs.x, v1 = r1*hs.y;
      // hi = truncated bf16, lo = RNE(residual): vh+vl == v to ~2^-17
      u32 u0 = __float_as_uint(v0), u1 = __float_as_uint(v1);
      u32 whi = (u0 >> 16) | (u1 & 0xffff0000u);
      float vl0 = v0 - __uint_as_float(u0 & 0xffff0000u);
      float vl1 = v1 - __uint_as_float(u1 & 0xffff0000u);
      int voff = e*256 + ((4*l) ^ ((e&7)<<4));
      *(u32*)(vA_hi + voff) = whi;
      *(u32*)(vA_lo + voff) = cvtpk(vl0, vl1);
      zpk[e] = cvtpk(z0, z1);
      hwd[e] = sp.z;
      acp[e] = cvtpk(ah.x+bh.x, ah.y+bh.y);
    }

    // ---- phase 2: acc = v @ Uh ----
    f32x4 acc[8];
    #pragma unroll
    for (int t=0; t<8; t++) acc[t] = (f32x4){0.f,0.f,0.f,0.f};
    matvec16(vA_hi, vA_lo, smem, l, acc);

    // ---- phase 3a: transpose acc (C-layout) -> accb f32, swizzled ----
    #pragma unroll
    for (int t=0; t<8; t++){
      #pragma unroll
      for (int r=0; r<4; r++){
        int e_ = agrp*4 + r;
        int c  = t*16 + arow;
        accb[e_*128 + (c ^ (agrp<<3))] = __float_as_uint(acc[t][r]);
      }
    }
    // ---- phase 3b: read back in phase-1 layout (ALL reads before any write) ----
    float2 xv[16];
    #pragma unroll
    for (int e=0; e<16; e++)
      xv[e] = *(float2*)&accb[e*128 + ((2*l) ^ ((e>>2)<<3))];

    // ---- phase 3c: ht = tanh(acc + Ah+Bh); m = (1-z)hs + z ht ; m -> vA ----
    float mf0[16], mf1[16];
    #pragma unroll
    for (int e=0; e<16; e++){
      float2 ac = bfp2(acp[e]);
      float2 zh = bfp2(zpk[e]);
      float2 hs = bfp2(hwd[e]);
      float ht0 = ftanh(xv[e].x + ac.x);
      float ht1 = ftanh(xv[e].y + ac.y);
      float m0 = (1.0f - zh.x)*hs.x + zh.x*ht0;
      float m1 = (1.0f - zh.y)*hs.y + zh.y*ht1;
      mf0[e] = m0; mf1[e] = m1;
      u32 u0 = __float_as_uint(m0), u1 = __float_as_uint(m1);
      u32 whi = (u0 >> 16) | (u1 & 0xffff0000u);
      float vl0 = m0 - __uint_as_float(u0 & 0xffff0000u);
      float vl1 = m1 - __uint_as_float(u1 & 0xffff0000u);
      int voff = e*256 + ((4*l) ^ ((e&7)<<4));
      *(u32*)(vA_hi + voff) = whi;
      *(u32*)(vA_lo + voff) = cvtpk(vl0, vl1);
    }

    // ---- phase 4: a2 = m @ Ws ----
    f32x4 a2[8];
    #pragma unroll
    for (int t=0; t<8; t++) a2[t] = (f32x4){0.f,0.f,0.f,0.f};
    matvec16(vA_hi, vA_lo, smem + SMEM_WST, l, a2);

    // ---- phase 5: attention scores (C-layout); CaT packed 16B/lane ----
    float ea[4];
    #pragma unroll
    for (int r=0; r<4; r++){
      int rid_r = __shfl(v_ridx, agrp*4 + r);
      uint4 cw = *(const uint4*)(CaT + (size_t)rid_r*D + arow*8);
      float2 c01 = bfp2(cw.x), c23 = bfp2(cw.y), c45 = bfp2(cw.z), c67 = bfp2(cw.w);
      float s = 0.f;
      s += fmaxf(a2[0][r]+c01.x,0.f)*wal[0];
      s += fmaxf(a2[1][r]+c01.y,0.f)*wal[1];
      s += fmaxf(a2[2][r]+c23.x,0.f)*wal[2];
      s += fmaxf(a2[3][r]+c23.y,0.f)*wal[3];
      s += fmaxf(a2[4][r]+c45.x,0.f)*wal[4];
      s += fmaxf(a2[5][r]+c45.y,0.f)*wal[5];
      s += fmaxf(a2[6][r]+c67.x,0.f)*wal[6];
      s += fmaxf(a2[7][r]+c67.y,0.f)*wal[7];
      s += __shfl_xor(s, 1); s += __shfl_xor(s, 2);
      s += __shfl_xor(s, 4); s += __shfl_xor(s, 8);
      ea[r] = __expf(s + bal);
    }

    // ---- phase 6: one pk atomic per edge = full 256B contiguous agg row ----
    #pragma unroll
    for (int e=0; e<16; e++){
      float ea_e = __shfl(ea[e & 3], (e >> 2) << 4);
      int obj_e  = __shfl(v_obj, e);
      int eg = eb + e;
      if (eg < E)
        atompk(aggh + (size_t)obj_e*D + c0, cvtpk(ea_e*mf0[e], ea_e*mf1[e]));
    }
    // batched tail: lane arow (group 0) handles edge eb+arow in ONE atomic pair
    {
      int srcl = (arow >> 2) << 4;
      float s0 = __shfl(ea[0], srcl);
      float s1 = __shfl(ea[1], srcl);
      float s2 = __shfl(ea[2], srcl);
      float s3 = __shfl(ea[3], srcl);
      int rr = arow & 3;
      float eav = (rr == 0) ? s0 : (rr == 1) ? s1 : (rr == 2) ? s2 : s3;
      if (agrp == 0 && (eb + arow) < E){
        atomicAdd(sum_exp + v_obj, eav);
        atomicMax(last_edge + v_obj, eb + arow);
      }
    }

    if (itn >= nIter) break;
    it = itn;
    v_ridx = n_ridx; v_rel = n_rel; v_sub = n_sub; v_obj = n_obj;
  }
}

// ---------------- finalize (4-node batched, dual output format) ----------------
__global__ __launch_bounds__(256) void final_kernel(
  const ushort_t* __restrict__ aggh, const float* __restrict__ sum_exp,
  const int* __restrict__ last_edge, const int* __restrict__ edges,
  const ushort_t* __restrict__ hq_tab, const ushort_t* __restrict__ Wh,
  const int* __restrict__ flag, void* __restrict__ out_base, int N)
{
  __shared__ float mb[4][D][4];
  int tid = threadIdx.x, w = tid >> 6, l = tid & 63;
  int c0 = 2*l, c1 = c0+1;
  int isf = *flag;
  float* out0f = (float*)out_base;
  float* out1f = out0f + (size_t)N*D;
  ushort_t* out0h = (ushort_t*)out_base;
  ushort_t* out1h = out0h + (size_t)N*D;
  int nIter = (N + 15) >> 4;
  for (int it = blockIdx.x; it < nIter; it += gridDim.x){
    int base = it*16 + w*4;
    int rq[4];
    #pragma unroll
    for (int e=0;e<4;e++){
      int n = base + e; if (n >= N) n = N-1;
      float se = sum_exp[n];
      float inv = (se > 0.f) ? (1.0f/se) : 0.f;
      float2 m = bfp2(*(const u32*)(aggh + (size_t)n*D + c0));
      mb[w][c0][e] = m.x*inv; mb[w][c1][e] = m.y*inv;
      int le = last_edge[n];
      rq[e] = (le >= 0) ? edges[(size_t)le*6] : 0;
    }
    float a0[4] = {0,0,0,0}, a1[4] = {0,0,0,0};
    #pragma unroll 4
    for (int kp=0; kp<64; kp++){
      float4 ma = *(float4*)&mb[w][2*kp][0];
      float4 mv = *(float4*)&mb[w][2*kp+1][0];
      float2 u0 = bfp2(*(const u32*)(Wh + (2*kp)*D + c0));
      float2 u1 = bfp2(*(const u32*)(Wh + (2*kp+1)*D + c0));
      a0[0] += ma.x*u0.x + mv.x*u1.x;  a1[0] += ma.x*u0.y + mv.x*u1.y;
      a0[1] += ma.y*u0.x + mv.y*u1.x;  a1[1] += ma.y*u0.y + mv.y*u1.y;
      a0[2] += ma.z*u0.x + mv.z*u1.x;  a1[2] += ma.z*u0.y + mv.z*u1.y;
      a0[3] += ma.w*u0.x + mv.w*u1.x;  a1[3] += ma.w*u0.y + mv.w*u1.y;
    }
    #pragma unroll
    for (int e=0;e<4;e++){
      int n = base + e; if (n >= N) continue;
      float r0 = fmaxf(a0[e], 0.f), r1 = fmaxf(a1[e], 0.f);
      u32 hqw = *(const u32*)(hq_tab + (size_t)rq[e]*D + c0);
      if (isf){
        float2 o0; o0.x = r0; o0.y = r1;
        *(float2*)(out0f + (size_t)n*D + c0) = o0;
        float2 hv = bfp2(hqw);
        *(float2*)(out1f + (size_t)n*D + c0) = hv;
      } else {
        *(u32*)(out0h + (size_t)n*D + c0) = packbf(r0, r1);
        *(u32*)(out1h + (size_t)n*D + c0) = hqw;
      }
    }
  }
}

extern "C" void kernel_launch(void* const* d_in, const int* in_sizes, int n_in,
                              void* d_out, int out_size, void* d_ws, size_t ws_size,
                              hipStream_t stream)
{
  const int* q_rel = (const int*)d_in[17];
  const int* edges = (const int*)d_in[18];

  int N   = in_sizes[0]/D;
  int NRE = in_sizes[1]/D;
  int NQ  = in_sizes[17];
  int E   = in_sizes[18]/6;

  char* ws = (char*)d_ws;
  size_t o = 0;
  auto alloc = [&](size_t bytes)->void*{
    void* p = ws + o; o += (bytes + 255) & ~(size_t)255; return p;
  };
  ushort_t* aggh  = (ushort_t*)alloc((size_t)N*D*2);
  float* sum_exp  = (float*)alloc((size_t)N*4);
  int*   lastedge = (int*)  alloc((size_t)N*4);
  int*   flag     = (int*)  alloc(256);

  ushort_t* canon[17];
  for (int i=0;i<17;i++) canon[i] = (ushort_t*)alloc((size_t)in_sizes[i]*2);

  ushort_t* hq_tab = (ushort_t*)alloc((size_t)NQ*D*2);
  ushort_t* CaT = (ushort_t*)alloc((size_t)NQ*D*2);
  u32* RELP = (u32*)alloc((size_t)NRE*192*4);
  u32* RIDP = (u32*)alloc((size_t)NQ*192*4);
  u32* SUB3 = (u32*)alloc((size_t)N*192*4);

  CvtArgs ca;
  for (int i=0;i<17;i++){ ca.src[i]=d_in[i]; ca.dst[i]=canon[i]; ca.n[i]=in_sizes[i]; }

  const ushort_t* hidden = canon[0];
  const ushort_t* rela   = canon[1];
  const ushort_t* Wz  = canon[2];
  const ushort_t* Uz  = canon[3];
  const ushort_t* bz  = canon[4];
  const ushort_t* Wr  = canon[5];
  const ushort_t* Ur  = canon[6];
  const ushort_t* br  = canon[7];
  const ushort_t* Whh = canon[8];
  const ushort_t* Uh  = canon[9];
  const ushort_t* bh  = canon[10];
  const ushort_t* Ws  = canon[11];
  const ushort_t* Wqr = canon[12];
  const ushort_t* bqr = canon[13];
  const ushort_t* wal = canon[14];
  const ushort_t* bal = canon[15];
  const ushort_t* W_h = canon[16];

  convert_kernel<<<1024, 256, 0, stream>>>(ca, (const u32*)d_in[1], flag,
                                           (u32*)aggh, sum_exp, lastedge, N);
  table_kernel<<<NRE+NQ, 128, 0, stream>>>(rela, Wz, Wr, Whh, Wqr, bz, br, bh, bqr,
                                           q_rel, hq_tab, RELP, RIDP, CaT, NRE, NQ);

  hipFuncSetAttribute(reinterpret_cast<const void*>(hu_kernel),
                      hipFuncAttributeMaxDynamicSharedMemorySize, HU_SMEM);
  hu_kernel<<<256, 512, HU_SMEM, stream>>>(hidden, Uz, Ur, SUB3, N);

  hipFuncSetAttribute(reinterpret_cast<const void*>(edge_kernel),
                      hipFuncAttributeMaxDynamicSharedMemorySize, EDGE_SMEM);
  edge_kernel<<<256, 512, EDGE_SMEM, stream>>>(edges, SUB3, RELP, RIDP, CaT,
                                               Uh, Ws, wal, bal, aggh, sum_exp, lastedge, E);
  final_kernel<<<1024, 256, 0, stream>>>(aggh, sum_exp, lastedge, edges, hq_tab, W_h,
                                         flag, d_out, N);
}